// Round 19
// baseline (242.859 us; speedup 1.0000x reference)
//
#include <hip/hip_runtime.h>

// ---------------------------------------------------------------------------
// MultiHeadAttention forward for MI355X (gfx950).
//   B=2, S=2048, D_MODEL=1024, H=16, DK=64.  Outputs: out [B,S,D] fp32 then
//   probs [B,H,S,S] fp32, concatenated flat in d_out.
// Round 19: attn widened to 8-wave blocks (512 thr, 128 q-rows, grid 512).
// K/V tiles shared by 8 waves -> per-wave staging halves (1 gload/buf/iter);
// LDS 48KB -> 3 blocks/CU x 8 waves = 24 waves/CU (vs 16), launch_bounds
// (512,6). vmcnt re-derived: pass1 ring vmcnt(1); pass2 deferred vmcnt(4).
// GEMMs = r18 (3-ring, XCD swizzle). Everything else unchanged.
// ---------------------------------------------------------------------------

typedef __bf16 bf16x8 __attribute__((ext_vector_type(8)));
typedef float f32x4 __attribute__((ext_vector_type(4)));

typedef const unsigned int __attribute__((address_space(1))) as1c_uint;
typedef unsigned int __attribute__((address_space(3))) as3_uint;

#define S_LEN 2048
#define DM 1024
#define NH 16
#define DK 64
#define BATCH 2
#define M_ROWS 4096  // BATCH * S_LEN
#define KE 0.18033688f  // 0.125 * log2(e): exp(s/8) = exp2(s*KE)

__device__ __forceinline__ unsigned short f2bfu(float f) {
  union { __bf16 b; unsigned short u; } cv;
  cv.b = (__bf16)f;   // fptrunc f32->bf16, RNE
  return cv.u;
}

__device__ __forceinline__ float bfu2f(unsigned short u) {
  union { float f; unsigned int i; } c;
  c.i = ((unsigned int)u) << 16;
  return c.f;
}

__device__ __forceinline__ void gload_lds16(const void* g, void* l) {
  __builtin_amdgcn_global_load_lds((as1c_uint*)g, (as3_uint*)l, 16, 0, 0);
}

// --------------------------- input convert (fp32->bf16) --------------------
__global__ __launch_bounds__(256) void cvt3_kernel(
    const float* __restrict__ q, const float* __restrict__ k,
    const float* __restrict__ v, unsigned short* __restrict__ oq,
    unsigned short* __restrict__ ok_, unsigned short* __restrict__ ov) {
  const float* in = blockIdx.z == 0 ? q : (blockIdx.z == 1 ? k : v);
  unsigned short* out = blockIdx.z == 0 ? oq : (blockIdx.z == 1 ? ok_ : ov);
  size_t i = (size_t)blockIdx.x * 256 + threadIdx.x;  // x4 elements
  float4 f = ((const float4*)in)[i];
  ushort4 u;
  u.x = f2bfu(f.x); u.y = f2bfu(f.y); u.z = f2bfu(f.z); u.w = f2bfu(f.w);
  ((ushort4*)out)[i] = u;
}

// ------------------- weight transpose + convert: WT[n][k]=W[k][n] ----------
__global__ __launch_bounds__(256) void wtrans_kernel(
    const float* __restrict__ w0, const float* __restrict__ w1,
    const float* __restrict__ w2, const float* __restrict__ w3,
    unsigned short* __restrict__ o0, unsigned short* __restrict__ o1,
    unsigned short* __restrict__ o2, unsigned short* __restrict__ o3) {
  const float* W = blockIdx.z == 0 ? w0 : (blockIdx.z == 1 ? w1 : (blockIdx.z == 2 ? w2 : w3));
  unsigned short* WT = blockIdx.z == 0 ? o0 : (blockIdx.z == 1 ? o1 : (blockIdx.z == 2 ? o2 : o3));
  __shared__ float tile[32][33];
  int tx = threadIdx.x & 31, ty = threadIdx.x >> 5;  // 32 x 8
  int bx = blockIdx.x * 32, by = blockIdx.y * 32;
#pragma unroll
  for (int i = 0; i < 32; i += 8)
    tile[ty + i][tx] = W[(size_t)(by + ty + i) * DM + bx + tx];
  __syncthreads();
#pragma unroll
  for (int i = 0; i < 32; i += 8)
    WT[(size_t)(bx + ty + i) * DM + by + tx] = f2bfu(tile[tx][ty + i]);
}

// ----------------------------- 128x128 bf16 GEMM ---------------------------
// r18: 3-buffer LDS ring, prefetch distance 2, counted vmcnt(4); XCD swizzle.
template <int EPI>
__device__ __forceinline__ void gemm_core(const unsigned short* __restrict__ A,
                                          const unsigned short* __restrict__ BT,
                                          const float* __restrict__ bias,
                                          void* __restrict__ C) {
  __shared__ __attribute__((aligned(16))) unsigned short As[3][128 * 32];
  __shared__ __attribute__((aligned(16))) unsigned short Bs[3][128 * 32];
  const int tid = threadIdx.x;
  const int w = tid >> 6, l = tid & 63;
  const int wr = w >> 1, wc = w & 1;        // 2x2 wave grid, 64x64 per wave
  const int fr = l & 15, fq = l >> 4;
  const int bid = blockIdx.y * 8 + blockIdx.x;
  const int swz = (bid & 7) * 32 + (bid >> 3);
  const int n0 = (swz & 7) * 128, m0 = (swz >> 3) * 128;
  const int srow = l >> 2;
  const int sk8 = (l & 3) * 8;
  f32x4 acc[4][4] = {};

#define GSTAGE(itn, buf)                                                      \
  {                                                                           \
    _Pragma("unroll") for (int c = 0; c < 2; c++) {                           \
      int rr = c * 64 + w * 16;                                               \
      gload_lds16(A + (size_t)(m0 + rr + srow) * DM + (itn) * 32 + sk8,       \
                  &As[buf][rr * 32]);                                         \
      gload_lds16(BT + (size_t)(n0 + rr + srow) * DM + (itn) * 32 + sk8,      \
                  &Bs[buf][rr * 32]);                                         \
    }                                                                         \
  }

  const int KIT = DM / 32;  // 32
  GSTAGE(0, 0);
  GSTAGE(1, 1);
  asm volatile("s_waitcnt vmcnt(4)" : : : "memory");
  __builtin_amdgcn_s_barrier();
  for (int it = 0; it < KIT; ++it) {
    const int cur = it % 3;
    if (it + 2 < KIT) GSTAGE(it + 2, (it + 2) % 3);
    bf16x8 af[4], bfv[4];
#pragma unroll
    for (int m = 0; m < 4; m++)
      af[m] = *(const bf16x8*)&As[cur][(wr * 64 + m * 16 + fr) * 32 + fq * 8];
#pragma unroll
    for (int n = 0; n < 4; n++)
      bfv[n] = *(const bf16x8*)&Bs[cur][(wc * 64 + n * 16 + fr) * 32 + fq * 8];
#pragma unroll
    for (int m = 0; m < 4; m++)
#pragma unroll
      for (int n = 0; n < 4; n++)
        acc[m][n] = __builtin_amdgcn_mfma_f32_16x16x32_bf16(af[m], bfv[n], acc[m][n], 0, 0, 0);
    if (it + 1 < KIT) {
      if (it + 2 < KIT) {
        asm volatile("s_waitcnt vmcnt(4)" : : : "memory");
      } else {
        asm volatile("s_waitcnt vmcnt(0)" : : : "memory");
      }
      __builtin_amdgcn_s_barrier();
    }
  }
#undef GSTAGE

#pragma unroll
  for (int m = 0; m < 4; m++) {
#pragma unroll
    for (int n = 0; n < 4; n++) {
      const int col = n0 + wc * 64 + n * 16 + fr;
      const float bv = bias[col];
#pragma unroll
      for (int j = 0; j < 4; j++) {
        const int row = m0 + wr * 64 + m * 16 + fq * 4 + j;
        const float v = acc[m][n][j] + bv;
        if (EPI == 0) {
          ((float*)C)[(size_t)row * DM + col] = v;
        } else {
          const int b = row >> 11, s = row & (S_LEN - 1);
          const int h = col >> 6, d = col & (DK - 1);
          ((unsigned short*)C)[(((size_t)b * NH + h) * S_LEN + s) * DK + d] = f2bfu(v);
        }
      }
    }
  }
}

__global__ __launch_bounds__(256) void gemm_qkv_kernel(
    const unsigned short* __restrict__ xq, const unsigned short* __restrict__ xk,
    const unsigned short* __restrict__ xv, const unsigned short* __restrict__ wq,
    const unsigned short* __restrict__ wk, const unsigned short* __restrict__ wv,
    const float* __restrict__ bq, const float* __restrict__ bk,
    const float* __restrict__ bv, unsigned short* __restrict__ oq,
    unsigned short* __restrict__ okk, unsigned short* __restrict__ ov) {
  const int z = blockIdx.z;
  const unsigned short* A = z == 0 ? xq : (z == 1 ? xk : xv);
  const unsigned short* BT = z == 0 ? wq : (z == 1 ? wk : wv);
  const float* bias = z == 0 ? bq : (z == 1 ? bk : bv);
  unsigned short* C = z == 0 ? oq : (z == 1 ? okk : ov);
  gemm_core<1>(A, BT, bias, C);
}

__global__ __launch_bounds__(256) void gemm_out_kernel(
    const unsigned short* __restrict__ A, const unsigned short* __restrict__ BT,
    const float* __restrict__ bias, float* __restrict__ C) {
  gemm_core<0>(A, BT, bias, C);
}

// --------------------- V transpose per head: [s][d] -> [d][s] --------------
__global__ __launch_bounds__(256) void vtrans_kernel(
    const unsigned short* __restrict__ V, unsigned short* __restrict__ VT) {
  __shared__ __attribute__((aligned(16))) unsigned short t[64][72];
  const int bh = blockIdx.y, s0 = blockIdx.x * 64;
  const unsigned short* v = V + ((size_t)bh * S_LEN + s0) * DK;
  const int tid = threadIdx.x;
#pragma unroll
  for (int i = 0; i < 4; i++) {
    int idx = tid + 256 * i;
    int r = idx >> 4, c4 = (idx & 15) * 4;
    *(ushort4*)&t[r][c4] = *(const ushort4*)(v + (size_t)r * DK + c4);
  }
  __syncthreads();
  unsigned short* o = VT + (size_t)bh * DK * S_LEN + s0;
#pragma unroll
  for (int i = 0; i < 4; i++) {
    int idx = tid + 256 * i;
    int d = idx >> 4, s4 = (idx & 15) * 4;
    ushort4 u;
    u.x = t[s4 + 0][d]; u.y = t[s4 + 1][d];
    u.z = t[s4 + 2][d]; u.w = t[s4 + 3][d];
    *(ushort4*)(o + (size_t)d * S_LEN + s4) = u;
  }
}

// ------------------------------- attention ---------------------------------
// grid 512 blocks x 512 threads (8 waves); wave owns 16 q-rows; block owns
// 128 q-rows. Head-per-XCD swizzle. Sb[4][64*64] shared by 8 waves: per-wave
// staging = 1 gload/buffer/iter (rows [w*8,w*8+8)). Pass 1 = 3-ring (Sb[0..2],
// distance 2, vmcnt(1)); pass 2 = K Sb[0..1] / V Sb[2..3] dbuf + deferred
// 256B/row NT stores (vmcnt(4)). Pfb[8][16][64] bf16 swizzled. LDS 48KB ->
// 3 blocks/CU = 24 waves/CU if VGPR<=~85 (launch_bounds(512,6)).
__global__ __launch_bounds__(512, 6) void attn_kernel(
    const unsigned short* __restrict__ Qp, const unsigned short* __restrict__ Kp,
    const unsigned short* __restrict__ VT, float* __restrict__ probs,
    unsigned short* __restrict__ attnc) {
  const int flat = blockIdx.y * 16 + blockIdx.x;
  const int xcd = flat & 7, r = flat >> 3;  // r in [0,64)
  const int bh = xcd * 4 + (r >> 4);        // 4 heads per XCD
  const int tile = r & 15;                  // 128-row q tile
  const int w = threadIdx.x >> 6, l = threadIdx.x & 63;
  const int fr = l & 15, fq = l >> 4;
  const int q0 = tile * 128 + w * 16;
  const int qrow = q0 + fr;
  const unsigned short* Qh = Qp + (size_t)bh * S_LEN * DK;
  const unsigned short* Kh = Kp + (size_t)bh * S_LEN * DK;
  const unsigned short* Vh = VT + (size_t)bh * DK * S_LEN;
  float* ph = probs + (size_t)bh * S_LEN * S_LEN;

  __shared__ __attribute__((aligned(16))) unsigned short Sb[4][64 * 64];
  __shared__ __attribute__((aligned(16))) unsigned short Pfb[8][16][64];  // bf16, swizzled

  // staging lane geometry: wave w covers rows [w*8, w*8+8); lane covers row
  // w*8 + (l>>3), granule (l&7)^(l>>3). LDS dest linear.
  const int srow8 = l >> 3;
  const int sgran = ((l & 7) ^ (l >> 3)) << 3;  // element offset in row
  const int kr7 = fr & 7;                       // read-side swizzle key

  bf16x8 qf[2];
  qf[0] = *(const bf16x8*)(Qh + (size_t)qrow * DK + fq * 8);
  qf[1] = *(const bf16x8*)(Qh + (size_t)qrow * DK + 32 + fq * 8);

  // ---------------- pass 1: row exp-sums, 3-deep K ring (Sb[0..2]) --------
  const int NIT = S_LEN / 64;

#define STAGE_P1(itn, buf)                                                    \
  gload_lds16(Kh + (size_t)((itn) * 64 + w * 8 + srow8) * DK + sgran,         \
              &Sb[buf][(w * 8 + srow8 - srow8) * 64 + (w * 8) * 64]);         \
  /* note: dest must be wave-uniform base; rewritten below */

#undef STAGE_P1
#define STAGE_P1(itn, buf)                                                    \
  gload_lds16(Kh + (size_t)((itn) * 64 + w * 8 + srow8) * DK + sgran,         \
              &Sb[buf][(w * 8) * 64]);

  float ps4[4] = {0.f, 0.f, 0.f, 0.f};
  STAGE_P1(0, 0);
  STAGE_P1(1, 1);
  asm volatile("s_waitcnt vmcnt(1)" : : : "memory");  // tile 0 ready
  __builtin_amdgcn_s_barrier();
  for (int it = 0; it < NIT; ++it) {
    const unsigned short* kcur = &Sb[it % 3][0];
    if (it + 2 < NIT) STAGE_P1(it + 2, (it + 2) % 3);
#pragma unroll
    for (int t = 0; t < 4; t++) {
      const int rk = t * 16 + fr;
      const bf16x8 a0 = *(const bf16x8*)&kcur[rk * 64 + ((fq ^ kr7) << 3)];
      const bf16x8 a1 = *(const bf16x8*)&kcur[rk * 64 + (((fq + 4) ^ kr7) << 3)];
      f32x4 s4 = {0.f, 0.f, 0.f, 0.f};
      s4 = __builtin_amdgcn_mfma_f32_16x16x32_bf16(a0, qf[0], s4, 0, 0, 0);
      s4 = __builtin_amdgcn_mfma_f32_16x16x32_bf16(a1, qf[1], s4, 0, 0, 0);
#pragma unroll
      for (int j = 0; j < 4; j++) ps4[j] += __builtin_amdgcn_exp2f(s4[j] * KE);
    }
    if (it + 1 < NIT) {
      if (it + 2 < NIT) {
        // own outstanding: 1 (it+1, last iter) + 1 (it+2, this iter).
        asm volatile("s_waitcnt vmcnt(1)" : : : "memory");
      } else {
        asm volatile("s_waitcnt vmcnt(0)" : : : "memory");
      }
      __builtin_amdgcn_s_barrier();
    }
  }
#undef STAGE_P1
  float psum = (ps4[0] + ps4[1]) + (ps4[2] + ps4[3]);
  psum += __shfl_xor(psum, 16, 64);
  psum += __shfl_xor(psum, 32, 64);
  const float pinv = 1.f / psum;
  __builtin_amdgcn_s_barrier();  // pass-1 reads done before pass-2 staging

  // ---------------- pass 2: deferred wide NT stores + PV ------------------
  f32x4 oacc[4] = {};
  const int strow = l >> 4;          // 0..3: row within 4-row store group
  const int stc16 = l & 15;          // col lane within row (16 x f32x4 = 256B)
  gload_lds16(Kh + (size_t)(w * 8 + srow8) * DK + sgran, &Sb[0][(w * 8) * 64]);
  gload_lds16(Vh + (size_t)(w * 8 + srow8) * S_LEN + sgran, &Sb[2][(w * 8) * 64]);
  asm volatile("s_waitcnt vmcnt(0)" : : : "memory");
  __builtin_amdgcn_s_barrier();
  for (int it = 0; it < NIT; ++it) {
    const int cur = it & 1;
    const int skb = it * 64;
    // (1) prefetch gloads first (1 K + 1 V per wave)
    if (it + 1 < NIT) {
      gload_lds16(Kh + (size_t)(skb + 64 + w * 8 + srow8) * DK + sgran,
                  &Sb[cur ^ 1][(w * 8) * 64]);
      gload_lds16(Vh + (size_t)(w * 8 + srow8) * S_LEN + (skb + 64) + sgran,
                  &Sb[2 + (cur ^ 1)][(w * 8) * 64]);
    }
    // (2) store previous iteration's probs from Pfb
    if (it > 0) {
      const int skbp = skb - 64;
#pragma unroll
      for (int i = 0; i < 4; i++) {
        const int row = 4 * i + strow;
        const int g2 = ((stc16 >> 1) ^ (row & 7));
        const ushort4 pb4 = *(const ushort4*)&Pfb[w][row][g2 * 8 + (l & 1) * 4];
        f32x4 pv4;
        pv4[0] = bfu2f(pb4.x); pv4[1] = bfu2f(pb4.y);
        pv4[2] = bfu2f(pb4.z); pv4[3] = bfu2f(pb4.w);
        __builtin_nontemporal_store(
            pv4, (f32x4*)(ph + (size_t)(q0 + row) * S_LEN + skbp + stc16 * 4));
      }
    }
    // (3) QK^T -> exp -> Pfb, PV
#pragma unroll
    for (int sub = 0; sub < 2; sub++) {
#pragma unroll
      for (int t = 0; t < 2; t++) {
        const int rk = sub * 32 + t * 16 + fr;
        const bf16x8 a0 = *(const bf16x8*)&Sb[cur][rk * 64 + ((fq ^ kr7) << 3)];
        const bf16x8 a1 = *(const bf16x8*)&Sb[cur][rk * 64 + (((fq + 4) ^ kr7) << 3)];
        f32x4 s4 = {0.f, 0.f, 0.f, 0.f};
        s4 = __builtin_amdgcn_mfma_f32_16x16x32_bf16(a0, qf[0], s4, 0, 0, 0);
        s4 = __builtin_amdgcn_mfma_f32_16x16x32_bf16(a1, qf[1], s4, 0, 0, 0);
        ushort4 pb;
#pragma unroll
        for (int j = 0; j < 4; j++)
          ((unsigned short*)&pb)[j] = f2bfu(__builtin_amdgcn_exp2f(s4[j] * KE) * pinv);
        const int g = (sub * 4 + t * 2 + (fq >> 1)) ^ kr7;
        *(ushort4*)&Pfb[w][fr][g * 8 + (fq & 1) * 4] = pb;
      }
      const int gr = (sub * 4 + fq) ^ kr7;
      const bf16x8 pa = *(const bf16x8*)&Pfb[w][fr][gr * 8];
      __builtin_amdgcn_s_setprio(1);
#pragma unroll
      for (int n = 0; n < 4; n++) {
        const bf16x8 vf =
            *(const bf16x8*)&Sb[2 + cur][(n * 16 + fr) * 64 + (((sub * 4 + fq) ^ kr7) << 3)];
        oacc[n] = __builtin_amdgcn_mfma_f32_16x16x32_bf16(pa, vf, oacc[n], 0, 0, 0);
      }
      __builtin_amdgcn_s_setprio(0);
    }
    // (4) barrier with counted wait
    if (it + 1 < NIT) {
      if (it == 0) {
        asm volatile("s_waitcnt vmcnt(0)" : : : "memory");
      } else {
        // outstanding: st(it-2)[<=4] + g(it+1)[2] + st(it-1)[4]; vmcnt(4)
        // retires st(it-2)+g(it+1), leaves st(it-1) in flight.
        asm volatile("s_waitcnt vmcnt(4)" : : : "memory");
      }
      __builtin_amdgcn_s_barrier();
    }
  }
  // final deferred store (data of iteration NIT-1)
  {
    const int skbp = (NIT - 1) * 64;
#pragma unroll
    for (int i = 0; i < 4; i++) {
      const int row = 4 * i + strow;
      const int g2 = ((stc16 >> 1) ^ (row & 7));
      const ushort4 pb4 = *(const ushort4*)&Pfb[w][row][g2 * 8 + (l & 1) * 4];
      f32x4 pv4;
      pv4[0] = bfu2f(pb4.x); pv4[1] = bfu2f(pb4.y);
      pv4[2] = bfu2f(pb4.z); pv4[3] = bfu2f(pb4.w);
      __builtin_nontemporal_store(
          pv4, (f32x4*)(ph + (size_t)(q0 + row) * S_LEN + skbp + stc16 * 4));
    }
  }

  const int b = bh >> 4, h = bh & (NH - 1);
#pragma unroll
  for (int n = 0; n < 4; n++) {
#pragma unroll
    for (int j = 0; j < 4; j++) {
      const int row = q0 + fq * 4 + j, col = h * DK + n * 16 + fr;
      attnc[(size_t)((size_t)b * S_LEN + row) * DM + col] = f2bfu(oacc[n][j]);
    }
  }
}

// ------------------------------- launcher ----------------------------------
extern "C" void kernel_launch(void* const* d_in, const int* in_sizes, int n_in,
                              void* d_out, int out_size, void* d_ws, size_t ws_size,
                              hipStream_t stream) {
  const float* query = (const float*)d_in[0];
  const float* key   = (const float*)d_in[1];
  const float* value = (const float*)d_in[2];
  const float* Wq = (const float*)d_in[3];
  const float* bq = (const float*)d_in[4];
  const float* Wk = (const float*)d_in[5];
  const float* bk = (const float*)d_in[6];
  const float* Wv = (const float*)d_in[7];
  const float* bv = (const float*)d_in[8];
  const float* Wo = (const float*)d_in[9];
  const float* bo = (const float*)d_in[10];

  char* ws = (char*)d_ws;
  const size_t XSZ = (size_t)M_ROWS * DM * 2;  // 8 MiB (bf16 [4096,1024])
  const size_t WSZ = (size_t)DM * DM * 2;      // 2 MiB (bf16 [1024,1024])
  unsigned short* xq  = (unsigned short*)(ws);
  unsigned short* xk  = (unsigned short*)(ws + XSZ);
  unsigned short* xv  = (unsigned short*)(ws + 2 * XSZ);
  unsigned short* wtq = (unsigned short*)(ws + 3 * XSZ);
  unsigned short* wtk = (unsigned short*)(ws + 3 * XSZ + WSZ);
  unsigned short* wtv = (unsigned short*)(ws + 3 * XSZ + 2 * WSZ);
  unsigned short* wto = (unsigned short*)(ws + 3 * XSZ + 3 * WSZ);
  unsigned short* qp  = (unsigned short*)(ws + 3 * XSZ + 4 * WSZ);
  unsigned short* kp  = (unsigned short*)(ws + 4 * XSZ + 4 * WSZ);
  unsigned short* vp  = (unsigned short*)(ws + 5 * XSZ + 4 * WSZ);
  unsigned short* vT    = xk;  // xk dead after gemm_qkv
  unsigned short* attnc = xq;  // xq dead after gemm_qkv

  float* out = (float*)d_out;
  float* probs = (float*)d_out + (size_t)BATCH * S_LEN * DM;

  cvt3_kernel<<<dim3(4096, 1, 3), 256, 0, stream>>>(query, key, value, xq, xk, xv);
  wtrans_kernel<<<dim3(32, 32, 4), 256, 0, stream>>>(Wq, Wk, Wv, Wo, wtq, wtk, wtv, wto);
  gemm_qkv_kernel<<<dim3(8, 32, 3), 256, 0, stream>>>(xq, xk, xv, wtq, wtk, wtv,
                                                      bq, bk, bv, qp, kp, vp);
  vtrans_kernel<<<dim3(32, 32), 256, 0, stream>>>(vp, vT);
  attn_kernel<<<dim3(16, 32), 512, 0, stream>>>(qp, kp, vT, probs, attnc);
  gemm_out_kernel<<<dim3(8, 32), 256, 0, stream>>>(attnc, wto, bo, out);
}

// Round 20
// 230.272 us; speedup vs baseline: 1.0547x; 1.0547x over previous
//
#include <hip/hip_runtime.h>

// ---------------------------------------------------------------------------
// MultiHeadAttention forward for MI355X (gfx950).
//   B=2, S=2048, D_MODEL=1024, H=16, DK=64.  Outputs: out [B,S,D] fp32 then
//   probs [B,H,S,S] fp32, concatenated flat in d_out.
// Round 20: REVERT to r18 (best: 230.4us) per r19 pre-commitment. r19's
// 8-wave attn blocks regressed (barrier lockstep width doubled). This is
// r18 verbatim: attn = r16 (4-wave, bf16 P staging, deferred 256B/row NT
// stores, 4 blocks/CU); GEMMs = 3-ring distance-2 + XCD swizzle.
// ---------------------------------------------------------------------------

typedef __bf16 bf16x8 __attribute__((ext_vector_type(8)));
typedef float f32x4 __attribute__((ext_vector_type(4)));

typedef const unsigned int __attribute__((address_space(1))) as1c_uint;
typedef unsigned int __attribute__((address_space(3))) as3_uint;

#define S_LEN 2048
#define DM 1024
#define NH 16
#define DK 64
#define BATCH 2
#define M_ROWS 4096  // BATCH * S_LEN
#define KE 0.18033688f  // 0.125 * log2(e): exp(s/8) = exp2(s*KE)

__device__ __forceinline__ unsigned short f2bfu(float f) {
  union { __bf16 b; unsigned short u; } cv;
  cv.b = (__bf16)f;   // fptrunc f32->bf16, RNE
  return cv.u;
}

__device__ __forceinline__ float bfu2f(unsigned short u) {
  union { float f; unsigned int i; } c;
  c.i = ((unsigned int)u) << 16;
  return c.f;
}

__device__ __forceinline__ void gload_lds16(const void* g, void* l) {
  __builtin_amdgcn_global_load_lds((as1c_uint*)g, (as3_uint*)l, 16, 0, 0);
}

// --------------------------- input convert (fp32->bf16) --------------------
__global__ __launch_bounds__(256) void cvt3_kernel(
    const float* __restrict__ q, const float* __restrict__ k,
    const float* __restrict__ v, unsigned short* __restrict__ oq,
    unsigned short* __restrict__ ok_, unsigned short* __restrict__ ov) {
  const float* in = blockIdx.z == 0 ? q : (blockIdx.z == 1 ? k : v);
  unsigned short* out = blockIdx.z == 0 ? oq : (blockIdx.z == 1 ? ok_ : ov);
  size_t i = (size_t)blockIdx.x * 256 + threadIdx.x;  // x4 elements
  float4 f = ((const float4*)in)[i];
  ushort4 u;
  u.x = f2bfu(f.x); u.y = f2bfu(f.y); u.z = f2bfu(f.z); u.w = f2bfu(f.w);
  ((ushort4*)out)[i] = u;
}

// ------------------- weight transpose + convert: WT[n][k]=W[k][n] ----------
__global__ __launch_bounds__(256) void wtrans_kernel(
    const float* __restrict__ w0, const float* __restrict__ w1,
    const float* __restrict__ w2, const float* __restrict__ w3,
    unsigned short* __restrict__ o0, unsigned short* __restrict__ o1,
    unsigned short* __restrict__ o2, unsigned short* __restrict__ o3) {
  const float* W = blockIdx.z == 0 ? w0 : (blockIdx.z == 1 ? w1 : (blockIdx.z == 2 ? w2 : w3));
  unsigned short* WT = blockIdx.z == 0 ? o0 : (blockIdx.z == 1 ? o1 : (blockIdx.z == 2 ? o2 : o3));
  __shared__ float tile[32][33];
  int tx = threadIdx.x & 31, ty = threadIdx.x >> 5;  // 32 x 8
  int bx = blockIdx.x * 32, by = blockIdx.y * 32;
#pragma unroll
  for (int i = 0; i < 32; i += 8)
    tile[ty + i][tx] = W[(size_t)(by + ty + i) * DM + bx + tx];
  __syncthreads();
#pragma unroll
  for (int i = 0; i < 32; i += 8)
    WT[(size_t)(bx + ty + i) * DM + by + tx] = f2bfu(tile[tx][ty + i]);
}

// ----------------------------- 128x128 bf16 GEMM ---------------------------
// C[m][n] = sum_k A[m][k]*BT[n][k] + bias[n].  M per z = 4096, N=K=1024.
// 3-buffer LDS ring, prefetch distance 2, counted vmcnt(4); XCD swizzle.
// EPI 0: fp32 row-major out.  EPI 1: bf16 out at [b][h][s][d] (QKV layout).
template <int EPI>
__device__ __forceinline__ void gemm_core(const unsigned short* __restrict__ A,
                                          const unsigned short* __restrict__ BT,
                                          const float* __restrict__ bias,
                                          void* __restrict__ C) {
  __shared__ __attribute__((aligned(16))) unsigned short As[3][128 * 32];
  __shared__ __attribute__((aligned(16))) unsigned short Bs[3][128 * 32];
  const int tid = threadIdx.x;
  const int w = tid >> 6, l = tid & 63;
  const int wr = w >> 1, wc = w & 1;        // 2x2 wave grid, 64x64 per wave
  const int fr = l & 15, fq = l >> 4;
  const int bid = blockIdx.y * 8 + blockIdx.x;
  const int swz = (bid & 7) * 32 + (bid >> 3);
  const int n0 = (swz & 7) * 128, m0 = (swz >> 3) * 128;
  const int srow = l >> 2;                  // staging: row within 16-row chunk
  const int sk8 = (l & 3) * 8;              // staging: k element offset
  f32x4 acc[4][4] = {};

#define GSTAGE(itn, buf)                                                      \
  {                                                                           \
    _Pragma("unroll") for (int c = 0; c < 2; c++) {                           \
      int rr = c * 64 + w * 16;                                               \
      gload_lds16(A + (size_t)(m0 + rr + srow) * DM + (itn) * 32 + sk8,       \
                  &As[buf][rr * 32]);                                         \
      gload_lds16(BT + (size_t)(n0 + rr + srow) * DM + (itn) * 32 + sk8,      \
                  &Bs[buf][rr * 32]);                                         \
    }                                                                         \
  }

  const int KIT = DM / 32;  // 32
  GSTAGE(0, 0);
  GSTAGE(1, 1);
  asm volatile("s_waitcnt vmcnt(4)" : : : "memory");
  __builtin_amdgcn_s_barrier();
  for (int it = 0; it < KIT; ++it) {
    const int cur = it % 3;
    if (it + 2 < KIT) GSTAGE(it + 2, (it + 2) % 3);
    bf16x8 af[4], bfv[4];
#pragma unroll
    for (int m = 0; m < 4; m++)
      af[m] = *(const bf16x8*)&As[cur][(wr * 64 + m * 16 + fr) * 32 + fq * 8];
#pragma unroll
    for (int n = 0; n < 4; n++)
      bfv[n] = *(const bf16x8*)&Bs[cur][(wc * 64 + n * 16 + fr) * 32 + fq * 8];
#pragma unroll
    for (int m = 0; m < 4; m++)
#pragma unroll
      for (int n = 0; n < 4; n++)
        acc[m][n] = __builtin_amdgcn_mfma_f32_16x16x32_bf16(af[m], bfv[n], acc[m][n], 0, 0, 0);
    if (it + 1 < KIT) {
      if (it + 2 < KIT) {
        asm volatile("s_waitcnt vmcnt(4)" : : : "memory");
      } else {
        asm volatile("s_waitcnt vmcnt(0)" : : : "memory");
      }
      __builtin_amdgcn_s_barrier();
    }
  }
#undef GSTAGE

#pragma unroll
  for (int m = 0; m < 4; m++) {
#pragma unroll
    for (int n = 0; n < 4; n++) {
      const int col = n0 + wc * 64 + n * 16 + fr;
      const float bv = bias[col];
#pragma unroll
      for (int j = 0; j < 4; j++) {
        const int row = m0 + wr * 64 + m * 16 + fq * 4 + j;
        const float v = acc[m][n][j] + bv;
        if (EPI == 0) {
          ((float*)C)[(size_t)row * DM + col] = v;
        } else {
          const int b = row >> 11, s = row & (S_LEN - 1);
          const int h = col >> 6, d = col & (DK - 1);
          ((unsigned short*)C)[(((size_t)b * NH + h) * S_LEN + s) * DK + d] = f2bfu(v);
        }
      }
    }
  }
}

__global__ __launch_bounds__(256) void gemm_qkv_kernel(
    const unsigned short* __restrict__ xq, const unsigned short* __restrict__ xk,
    const unsigned short* __restrict__ xv, const unsigned short* __restrict__ wq,
    const unsigned short* __restrict__ wk, const unsigned short* __restrict__ wv,
    const float* __restrict__ bq, const float* __restrict__ bk,
    const float* __restrict__ bv, unsigned short* __restrict__ oq,
    unsigned short* __restrict__ okk, unsigned short* __restrict__ ov) {
  const int z = blockIdx.z;
  const unsigned short* A = z == 0 ? xq : (z == 1 ? xk : xv);
  const unsigned short* BT = z == 0 ? wq : (z == 1 ? wk : wv);
  const float* bias = z == 0 ? bq : (z == 1 ? bk : bv);
  unsigned short* C = z == 0 ? oq : (z == 1 ? okk : ov);
  gemm_core<1>(A, BT, bias, C);
}

__global__ __launch_bounds__(256) void gemm_out_kernel(
    const unsigned short* __restrict__ A, const unsigned short* __restrict__ BT,
    const float* __restrict__ bias, float* __restrict__ C) {
  gemm_core<0>(A, BT, bias, C);
}

// --------------------- V transpose per head: [s][d] -> [d][s] --------------
__global__ __launch_bounds__(256) void vtrans_kernel(
    const unsigned short* __restrict__ V, unsigned short* __restrict__ VT) {
  __shared__ __attribute__((aligned(16))) unsigned short t[64][72];
  const int bh = blockIdx.y, s0 = blockIdx.x * 64;
  const unsigned short* v = V + ((size_t)bh * S_LEN + s0) * DK;
  const int tid = threadIdx.x;
#pragma unroll
  for (int i = 0; i < 4; i++) {
    int idx = tid + 256 * i;
    int r = idx >> 4, c4 = (idx & 15) * 4;
    *(ushort4*)&t[r][c4] = *(const ushort4*)(v + (size_t)r * DK + c4);
  }
  __syncthreads();
  unsigned short* o = VT + (size_t)bh * DK * S_LEN + s0;
#pragma unroll
  for (int i = 0; i < 4; i++) {
    int idx = tid + 256 * i;
    int d = idx >> 4, s4 = (idx & 15) * 4;
    ushort4 u;
    u.x = t[s4 + 0][d]; u.y = t[s4 + 1][d];
    u.z = t[s4 + 2][d]; u.w = t[s4 + 3][d];
    *(ushort4*)(o + (size_t)d * S_LEN + s4) = u;
  }
}

// ------------------------------- attention (r16) ---------------------------
// grid 1024 blocks, 4 waves; wave owns 16 q-rows; block owns 64 q-rows.
// Head-per-XCD swizzle (K/V L2-resident). Sb[4][64*64] (32KB): pass 1 =
// 3-deep K ring (distance 2, counted vmcnt(2)); pass 2 = K dbuf Sb[0..1],
// V dbuf Sb[2..3]. P staged as bf16 in Pfb[4][16][64] (8KB, XOR-swizzled).
// LDS 40KB -> 4 blocks/CU. Pass-2 NT stores (256B/row) deferred one iter.
__global__ __launch_bounds__(256, 4) void attn_kernel(
    const unsigned short* __restrict__ Qp, const unsigned short* __restrict__ Kp,
    const unsigned short* __restrict__ VT, float* __restrict__ probs,
    unsigned short* __restrict__ attnc) {
  const int flat = blockIdx.y * 32 + blockIdx.x;
  const int xcd = flat & 7, r = flat >> 3;
  const int bh = xcd * 4 + (r >> 5);        // 4 heads per XCD
  const int tile = r & 31;
  const int w = threadIdx.x >> 6, l = threadIdx.x & 63;
  const int fr = l & 15, fq = l >> 4;
  const int q0 = tile * 64 + w * 16;
  const int qrow = q0 + fr;
  const unsigned short* Qh = Qp + (size_t)bh * S_LEN * DK;
  const unsigned short* Kh = Kp + (size_t)bh * S_LEN * DK;
  const unsigned short* Vh = VT + (size_t)bh * DK * S_LEN;
  float* ph = probs + (size_t)bh * S_LEN * S_LEN;

  __shared__ __attribute__((aligned(16))) unsigned short Sb[4][64 * 64];
  __shared__ __attribute__((aligned(16))) unsigned short Pfb[4][16][64];  // bf16, swizzled

  const int srow8 = l >> 3;
  const int sgran = ((l & 7) ^ (l >> 3)) << 3;  // element offset in row
  const int kr7 = fr & 7;                       // read-side swizzle key

  bf16x8 qf[2];
  qf[0] = *(const bf16x8*)(Qh + (size_t)qrow * DK + fq * 8);
  qf[1] = *(const bf16x8*)(Qh + (size_t)qrow * DK + 32 + fq * 8);

  // ---------------- pass 1: row exp-sums, 3-deep K ring (Sb[0..2]) --------
  const int NIT = S_LEN / 64;

#define STAGE_P1(itn, buf)                                                    \
  {                                                                           \
    _Pragma("unroll") for (int i = 0; i < 2; i++)                             \
        gload_lds16(Kh + (size_t)((itn) * 64 + w * 16 + i * 8 + srow8) * DK + \
                        sgran,                                                \
                    &Sb[buf][(w * 16 + i * 8) * 64]);                         \
  }

  float ps4[4] = {0.f, 0.f, 0.f, 0.f};
  STAGE_P1(0, 0);
  STAGE_P1(1, 1);
  asm volatile("s_waitcnt vmcnt(2)" : : : "memory");  // tile 0 ready
  __builtin_amdgcn_s_barrier();
  for (int it = 0; it < NIT; ++it) {
    const unsigned short* kcur = &Sb[it % 3][0];
    if (it + 2 < NIT) STAGE_P1(it + 2, (it + 2) % 3);
#pragma unroll
    for (int t = 0; t < 4; t++) {
      const int rk = t * 16 + fr;
      const bf16x8 a0 = *(const bf16x8*)&kcur[rk * 64 + ((fq ^ kr7) << 3)];
      const bf16x8 a1 = *(const bf16x8*)&kcur[rk * 64 + (((fq + 4) ^ kr7) << 3)];
      f32x4 s4 = {0.f, 0.f, 0.f, 0.f};
      s4 = __builtin_amdgcn_mfma_f32_16x16x32_bf16(a0, qf[0], s4, 0, 0, 0);
      s4 = __builtin_amdgcn_mfma_f32_16x16x32_bf16(a1, qf[1], s4, 0, 0, 0);
#pragma unroll
      for (int j = 0; j < 4; j++) ps4[j] += __builtin_amdgcn_exp2f(s4[j] * KE);
    }
    if (it + 1 < NIT) {
      if (it + 2 < NIT) {
        asm volatile("s_waitcnt vmcnt(2)" : : : "memory");
      } else {
        asm volatile("s_waitcnt vmcnt(0)" : : : "memory");
      }
      __builtin_amdgcn_s_barrier();
    }
  }
#undef STAGE_P1
  float psum = (ps4[0] + ps4[1]) + (ps4[2] + ps4[3]);
  psum += __shfl_xor(psum, 16, 64);
  psum += __shfl_xor(psum, 32, 64);
  const float pinv = 1.f / psum;
  __builtin_amdgcn_s_barrier();  // pass-1 reads done before pass-2 staging

  // ---------------- pass 2: deferred wide NT stores + PV ------------------
  f32x4 oacc[4] = {};
  const int strow = l >> 4;          // 0..3: row within 4-row store group
  const int stc16 = l & 15;          // col lane within row (16 x f32x4 = 256B)
#pragma unroll
  for (int i = 0; i < 2; i++) {
    gload_lds16(Kh + (size_t)(w * 16 + i * 8 + srow8) * DK + sgran,
                &Sb[0][(w * 16 + i * 8) * 64]);
    gload_lds16(Vh + (size_t)(w * 16 + i * 8 + srow8) * S_LEN + sgran,
                &Sb[2][(w * 16 + i * 8) * 64]);
  }
  asm volatile("s_waitcnt vmcnt(0)" : : : "memory");
  __builtin_amdgcn_s_barrier();
  for (int it = 0; it < NIT; ++it) {
    const int cur = it & 1;
    const int skb = it * 64;
    if (it + 1 < NIT) {
#pragma unroll
      for (int i = 0; i < 2; i++) {
        gload_lds16(Kh + (size_t)(skb + 64 + w * 16 + i * 8 + srow8) * DK + sgran,
                    &Sb[cur ^ 1][(w * 16 + i * 8) * 64]);
        gload_lds16(Vh + (size_t)(w * 16 + i * 8 + srow8) * S_LEN + (skb + 64) + sgran,
                    &Sb[2 + (cur ^ 1)][(w * 16 + i * 8) * 64]);
      }
    }
    if (it > 0) {
      const int skbp = skb - 64;
#pragma unroll
      for (int i = 0; i < 4; i++) {
        const int row = 4 * i + strow;
        const int g2 = ((stc16 >> 1) ^ (row & 7));
        const ushort4 pb4 = *(const ushort4*)&Pfb[w][row][g2 * 8 + (l & 1) * 4];
        f32x4 pv4;
        pv4[0] = bfu2f(pb4.x); pv4[1] = bfu2f(pb4.y);
        pv4[2] = bfu2f(pb4.z); pv4[3] = bfu2f(pb4.w);
        __builtin_nontemporal_store(
            pv4, (f32x4*)(ph + (size_t)(q0 + row) * S_LEN + skbp + stc16 * 4));
      }
    }
#pragma unroll
    for (int sub = 0; sub < 2; sub++) {
#pragma unroll
      for (int t = 0; t < 2; t++) {
        const int rk = sub * 32 + t * 16 + fr;
        const bf16x8 a0 = *(const bf16x8*)&Sb[cur][rk * 64 + ((fq ^ kr7) << 3)];
        const bf16x8 a1 = *(const bf16x8*)&Sb[cur][rk * 64 + (((fq + 4) ^ kr7) << 3)];
        f32x4 s4 = {0.f, 0.f, 0.f, 0.f};
        s4 = __builtin_amdgcn_mfma_f32_16x16x32_bf16(a0, qf[0], s4, 0, 0, 0);
        s4 = __builtin_amdgcn_mfma_f32_16x16x32_bf16(a1, qf[1], s4, 0, 0, 0);
        ushort4 pb;
#pragma unroll
        for (int j = 0; j < 4; j++)
          ((unsigned short*)&pb)[j] = f2bfu(__builtin_amdgcn_exp2f(s4[j] * KE) * pinv);
        const int g = (sub * 4 + t * 2 + (fq >> 1)) ^ kr7;
        *(ushort4*)&Pfb[w][fr][g * 8 + (fq & 1) * 4] = pb;
      }
      const int gr = (sub * 4 + fq) ^ kr7;
      const bf16x8 pa = *(const bf16x8*)&Pfb[w][fr][gr * 8];
      __builtin_amdgcn_s_setprio(1);
#pragma unroll
      for (int n = 0; n < 4; n++) {
        const bf16x8 vf =
            *(const bf16x8*)&Sb[2 + cur][(n * 16 + fr) * 64 + (((sub * 4 + fq) ^ kr7) << 3)];
        oacc[n] = __builtin_amdgcn_mfma_f32_16x16x32_bf16(pa, vf, oacc[n], 0, 0, 0);
      }
      __builtin_amdgcn_s_setprio(0);
    }
    if (it + 1 < NIT) {
      if (it == 0) {
        asm volatile("s_waitcnt vmcnt(0)" : : : "memory");
      } else {
        asm volatile("s_waitcnt vmcnt(4)" : : : "memory");
      }
      __builtin_amdgcn_s_barrier();
    }
  }
  {
    const int skbp = (NIT - 1) * 64;
#pragma unroll
    for (int i = 0; i < 4; i++) {
      const int row = 4 * i + strow;
      const int g2 = ((stc16 >> 1) ^ (row & 7));
      const ushort4 pb4 = *(const ushort4*)&Pfb[w][row][g2 * 8 + (l & 1) * 4];
      f32x4 pv4;
      pv4[0] = bfu2f(pb4.x); pv4[1] = bfu2f(pb4.y);
      pv4[2] = bfu2f(pb4.z); pv4[3] = bfu2f(pb4.w);
      __builtin_nontemporal_store(
          pv4, (f32x4*)(ph + (size_t)(q0 + row) * S_LEN + skbp + stc16 * 4));
    }
  }

  const int b = bh >> 4, h = bh & (NH - 1);
#pragma unroll
  for (int n = 0; n < 4; n++) {
#pragma unroll
    for (int j = 0; j < 4; j++) {
      const int row = q0 + fq * 4 + j, col = h * DK + n * 16 + fr;
      attnc[(size_t)((size_t)b * S_LEN + row) * DM + col] = f2bfu(oacc[n][j]);
    }
  }
}

// ------------------------------- launcher ----------------------------------
extern "C" void kernel_launch(void* const* d_in, const int* in_sizes, int n_in,
                              void* d_out, int out_size, void* d_ws, size_t ws_size,
                              hipStream_t stream) {
  const float* query = (const float*)d_in[0];
  const float* key   = (const float*)d_in[1];
  const float* value = (const float*)d_in[2];
  const float* Wq = (const float*)d_in[3];
  const float* bq = (const float*)d_in[4];
  const float* Wk = (const float*)d_in[5];
  const float* bk = (const float*)d_in[6];
  const float* Wv = (const float*)d_in[7];
  const float* bv = (const float*)d_in[8];
  const float* Wo = (const float*)d_in[9];
  const float* bo = (const float*)d_in[10];

  char* ws = (char*)d_ws;
  const size_t XSZ = (size_t)M_ROWS * DM * 2;  // 8 MiB (bf16 [4096,1024])
  const size_t WSZ = (size_t)DM * DM * 2;      // 2 MiB (bf16 [1024,1024])
  unsigned short* xq  = (unsigned short*)(ws);
  unsigned short* xk  = (unsigned short*)(ws + XSZ);
  unsigned short* xv  = (unsigned short*)(ws + 2 * XSZ);
  unsigned short* wtq = (unsigned short*)(ws + 3 * XSZ);
  unsigned short* wtk = (unsigned short*)(ws + 3 * XSZ + WSZ);
  unsigned short* wtv = (unsigned short*)(ws + 3 * XSZ + 2 * WSZ);
  unsigned short* wto = (unsigned short*)(ws + 3 * XSZ + 3 * WSZ);
  unsigned short* qp  = (unsigned short*)(ws + 3 * XSZ + 4 * WSZ);
  unsigned short* kp  = (unsigned short*)(ws + 4 * XSZ + 4 * WSZ);
  unsigned short* vp  = (unsigned short*)(ws + 5 * XSZ + 4 * WSZ);
  unsigned short* vT    = xk;  // xk dead after gemm_qkv
  unsigned short* attnc = xq;  // xq dead after gemm_qkv

  float* out = (float*)d_out;
  float* probs = (float*)d_out + (size_t)BATCH * S_LEN * DM;

  cvt3_kernel<<<dim3(4096, 1, 3), 256, 0, stream>>>(query, key, value, xq, xk, xv);
  wtrans_kernel<<<dim3(32, 32, 4), 256, 0, stream>>>(Wq, Wk, Wv, Wo, wtq, wtk, wtv, wto);
  gemm_qkv_kernel<<<dim3(8, 32, 3), 256, 0, stream>>>(xq, xk, xv, wtq, wtk, wtv,
                                                      bq, bk, bv, qp, kp, vp);
  vtrans_kernel<<<dim3(32, 32), 256, 0, stream>>>(vp, vT);
  attn_kernel<<<dim3(32, 32), 256, 0, stream>>>(qp, kp, vT, probs, attnc);
  gemm_out_kernel<<<dim3(8, 32), 256, 0, stream>>>(attnc, wto, bo, out);
}